// Round 8
// baseline (95.761 us; speedup 1.0000x reference)
//
#include <hip/hip_runtime.h>

// Problem constants: logits (N=4, C=19, H=512, W=1024) float32; target unused.
#define NCLS 19
#define NSMP 4
#define HW   (512 * 1024)
#define NSEG (NSMP * NCLS)   // 76 segments
#define NBLK 512

// ws layout (floats): [0..76) S1 | [76..152) S2 | [152..228) cnt | [228] done-counter
// memset node zeroes all 229 floats each call (replay-deterministic).
//
// R8: R7's main body (best so far, ~3.5 TB/s read = at the demonstrated
// machine read ceiling; m13 copy read-side = 3.15) + final reduction FUSED
// via last-block-done (threadfence + device-scope counter), removing the
// cl_final node and one graph gap.
__global__ __launch_bounds__(256) void cl_main(const float* __restrict__ logits,
                                               float* __restrict__ ws,
                                               float* __restrict__ out) {
    __shared__ float sb[3 * NCLS];   // [S1_19 | S2_19 | cnt_19]
    __shared__ int   lastFlag;
    __shared__ float red[128];
    const int tid = threadIdx.x;
    if (tid < 3 * NCLS) sb[tid] = 0.0f;
    __syncthreads();

    const int    n    = blockIdx.x >> 7;                      // 128 blocks per sample
    const size_t bpix = (size_t)(blockIdx.x & 127) * 4096;    // block pixel offset
    const float* base = logits + (size_t)n * NCLS * HW + bpix + (size_t)tid * 4;

    #pragma unroll
    for (int r = 0; r < 4; ++r) {
        float4 v[NCLS];
        #pragma unroll
        for (int c = 0; c < NCLS; ++c) {
            v[c] = *(const float4*)(base + (size_t)c * HW + (size_t)r * 1024);
        }
        asm volatile("" ::: "memory");

        float s1[4], s2[4], mv[4];
        int   mi[4];
        {
            const float a0[4] = {v[0].x, v[0].y, v[0].z, v[0].w};
            #pragma unroll
            for (int j = 0; j < 4; ++j) {
                s1[j] = a0[j]; s2[j] = a0[j] * a0[j]; mv[j] = a0[j]; mi[j] = 0;
            }
        }
        #pragma unroll
        for (int c = 1; c < NCLS; ++c) {
            const float a[4] = {v[c].x, v[c].y, v[c].z, v[c].w};
            #pragma unroll
            for (int j = 0; j < 4; ++j) {
                s1[j] += a[j];
                s2[j]  = fmaf(a[j], a[j], s2[j]);
                if (a[j] > mv[j]) { mv[j] = a[j]; mi[j] = c; }  // strict > = first-idx argmax
            }
        }

        #pragma unroll
        for (int j = 0; j < 4; ++j) {
            atomicAdd(&sb[mi[j]],      s1[j]);
            atomicAdd(&sb[19 + mi[j]], s2[j]);
            atomicAdd(&sb[38 + mi[j]], 1.0f);
        }
        asm volatile("" ::: "memory");
    }
    __syncthreads();

    if (tid < NCLS) {
        const int seg = n * NCLS + tid;
        atomicAdd(&ws[seg],            sb[tid]);
        atomicAdd(&ws[NSEG + seg],     sb[19 + tid]);
        atomicAdd(&ws[2 * NSEG + seg], sb[38 + tid]);
    }
    // Wait for this block's seg-atomics to drain (syncthreads waits vmcnt),
    // then bump the done-counter; the 512th arriver does the final reduce.
    __syncthreads();
    __threadfence();
    if (tid == 0) {
        unsigned old = atomicAdd((unsigned*)(ws + 3 * NSEG), 1u);
        lastFlag = (old == NBLK - 1);
    }
    __syncthreads();

    if (lastFlag) {
        __threadfence();   // acquire: other blocks' adds visible (paired with their fences)
        float v = 0.0f;
        if (tid < NSEG) {
            const float S1  = ws[tid];
            const float S2  = ws[NSEG + tid];
            const float cnt = ws[2 * NSEG + tid];
            const float K   = fmaxf(cnt, 1.0f) * (float)NCLS;
            const float sq  = fmaxf(S2 - S1 * S1 / K, 0.0f);
            v = (cnt > 0.0f) ? sqrtf(sq) : 0.0f;
        }
        if (tid < 128) red[tid] = v;
        __syncthreads();
        #pragma unroll
        for (int s = 64; s > 0; s >>= 1) {
            if (tid < s) red[tid] += red[tid + s];
            __syncthreads();
        }
        if (tid == 0) out[0] = red[0] * 0.25f;
    }
}

extern "C" void kernel_launch(void* const* d_in, const int* in_sizes, int n_in,
                              void* d_out, int out_size, void* d_ws, size_t ws_size,
                              hipStream_t stream) {
    const float* logits = (const float*)d_in[0];
    // d_in[1] (target) is unused by the reference computation.
    float* ws  = (float*)d_ws;
    float* out = (float*)d_out;

    hipMemsetAsync(ws, 0, (3 * NSEG + 1) * sizeof(float), stream);
    cl_main<<<NBLK, 256, 0, stream>>>(logits, ws, out);
}

// Round 9
// 65.214 us; speedup vs baseline: 1.4684x; 1.4684x over previous
//
#include <hip/hip_runtime.h>

// Problem constants: logits (N=4, C=19, H=512, W=1024) float32; target unused.
#define NCLS 19
#define NSMP 4
#define HW   (512 * 1024)
#define NSEG (NSMP * NCLS)   // 76 segments

// ws layout (floats): [0..76) = S1, [76..152) = S2, [152..228) = cnt
//
// R9 probe (burst-length / stream-count): c-OUTER ordering. Block covers 4096
// contiguous pixels; for each plane c it reads its 16 KB chunk CONTIGUOUSLY
// (4 x 4KB wave bursts) before jumping to plane c+1 — long sequential DRAM/L3
// bursts, 1 stream at a time, vs R2/R7's 19-way 4KB round-robin. 1-deep
// software pipeline (issue plane c+1's 4 loads, then consume plane c) keeps
// ~32+ lines in flight per wave. Per-thread state for 16 px lives in
// registers, all statically indexed (~111 VGPR, no spill). Tail = R7 exactly.
__global__ __launch_bounds__(256) void cl_main(const float* __restrict__ logits,
                                               float* __restrict__ ws) {
    __shared__ float sb[3 * NCLS];   // [S1_19 | S2_19 | cnt_19]
    const int tid = threadIdx.x;
    if (tid < 3 * NCLS) sb[tid] = 0.0f;
    __syncthreads();

    const int    n    = blockIdx.x >> 7;                      // 128 blocks per sample
    const size_t bpix = (size_t)(blockIdx.x & 127) * 4096;    // block pixel offset
    const float* base = logits + (size_t)n * NCLS * HW + bpix + (size_t)tid * 4;

    float s1[16], s2[16], mv[16];
    int   mi[16];

    float4 va[4], vb[4];
    #pragma unroll
    for (int r = 0; r < 4; ++r)
        va[r] = *(const float4*)(base + (size_t)r * 1024);    // plane 0

#define STEPC(CUR, NXT, C, DOLOAD)                                             \
    do {                                                                       \
        if (DOLOAD) {                                                          \
            _Pragma("unroll")                                                  \
            for (int r = 0; r < 4; ++r)                                        \
                NXT[r] = *(const float4*)(base + (size_t)((C) + 1) * HW +      \
                                          (size_t)r * 1024);                   \
        }                                                                      \
        _Pragma("unroll")                                                      \
        for (int r = 0; r < 4; ++r) {                                          \
            const float a[4] = {CUR[r].x, CUR[r].y, CUR[r].z, CUR[r].w};       \
            _Pragma("unroll")                                                  \
            for (int j = 0; j < 4; ++j) {                                      \
                const int jj = r * 4 + j;  /* compile-time constant */         \
                if ((C) == 0) {                                                \
                    s1[jj] = a[j]; s2[jj] = a[j] * a[j];                       \
                    mv[jj] = a[j]; mi[jj] = 0;                                 \
                } else {                                                       \
                    s1[jj] += a[j];                                            \
                    s2[jj]  = fmaf(a[j], a[j], s2[jj]);                        \
                    if (a[j] > mv[jj]) { mv[jj] = a[j]; mi[jj] = (C); }        \
                }                                                              \
            }                                                                  \
        }                                                                      \
        asm volatile("" ::: "memory");  /* bound lookahead to 1 plane */       \
    } while (0)

    STEPC(va, vb,  0, true);
    STEPC(vb, va,  1, true);
    STEPC(va, vb,  2, true);
    STEPC(vb, va,  3, true);
    STEPC(va, vb,  4, true);
    STEPC(vb, va,  5, true);
    STEPC(va, vb,  6, true);
    STEPC(vb, va,  7, true);
    STEPC(va, vb,  8, true);
    STEPC(vb, va,  9, true);
    STEPC(va, vb, 10, true);
    STEPC(vb, va, 11, true);
    STEPC(va, vb, 12, true);
    STEPC(vb, va, 13, true);
    STEPC(va, vb, 14, true);
    STEPC(vb, va, 15, true);
    STEPC(va, vb, 16, true);
    STEPC(vb, va, 17, true);
    STEPC(va, vb, 18, false);
#undef STEPC

    #pragma unroll
    for (int j = 0; j < 16; ++j) {
        atomicAdd(&sb[mi[j]],      s1[j]);
        atomicAdd(&sb[19 + mi[j]], s2[j]);
        atomicAdd(&sb[38 + mi[j]], 1.0f);
    }
    __syncthreads();

    if (tid < NCLS) {
        const int seg = n * NCLS + tid;
        atomicAdd(&ws[seg],            sb[tid]);
        atomicAdd(&ws[NSEG + seg],     sb[19 + tid]);
        atomicAdd(&ws[2 * NSEG + seg], sb[38 + tid]);
    }
}

__global__ void cl_final(const float* __restrict__ ws, float* __restrict__ out) {
    __shared__ float red[128];
    const int i = threadIdx.x;
    float v = 0.0f;
    if (i < NSEG) {
        const float S1  = ws[i];
        const float S2  = ws[NSEG + i];
        const float cnt = ws[2 * NSEG + i];
        const float K   = fmaxf(cnt, 1.0f) * (float)NCLS;
        const float sq  = fmaxf(S2 - S1 * S1 / K, 0.0f);
        v = (cnt > 0.0f) ? sqrtf(sq) : 0.0f;
    }
    red[i] = v;
    __syncthreads();
    #pragma unroll
    for (int s = 64; s > 0; s >>= 1) {
        if (i < s) red[i] += red[i + s];
        __syncthreads();
    }
    if (i == 0) out[0] = red[0] / (float)NSMP;
}

extern "C" void kernel_launch(void* const* d_in, const int* in_sizes, int n_in,
                              void* d_out, int out_size, void* d_ws, size_t ws_size,
                              hipStream_t stream) {
    const float* logits = (const float*)d_in[0];
    // d_in[1] (target) is unused by the reference computation.
    float* ws  = (float*)d_ws;
    float* out = (float*)d_out;

    hipMemsetAsync(ws, 0, 3 * NSEG * sizeof(float), stream);
    cl_main<<<512, 256, 0, stream>>>(logits, ws);
    cl_final<<<1, 128, 0, stream>>>(ws, out);
}